// Round 3
// baseline (6305.820 us; speedup 1.0000x reference)
//
#include <hip/hip_runtime.h>

typedef __attribute__((ext_vector_type(8))) short s8v;   // 8 x bf16 (4 VGPRs)
typedef __attribute__((ext_vector_type(4))) float f4v;   // MFMA accumulator

#define BB 8
#define TT 500
#define UU 120
#define UP1 121
#define VV 128
#define HH 320
#define G4 1280

// ---------------- helpers ----------------
__device__ __forceinline__ unsigned short f2bf(float x) {
  unsigned u = __builtin_bit_cast(unsigned, x);
  unsigned r = (u + 0x7FFFu + ((u >> 16) & 1u)) >> 16;  // RNE
  return (unsigned short)r;
}
__device__ __forceinline__ float sigf(float x)   { return 1.f / (1.f + __expf(-x)); }
__device__ __forceinline__ float tanh_f(float x) { return 2.f / (1.f + __expf(-2.f * x)) - 1.f; }

// relaxed agent-scope atomics: sc1 path, bypass stale L1/L2, no cache maintenance
__device__ __forceinline__ unsigned long long ald64(const unsigned long long* p) {
  return __hip_atomic_load((unsigned long long*)p, __ATOMIC_RELAXED, __HIP_MEMORY_SCOPE_AGENT);
}
__device__ __forceinline__ void ast32(unsigned* p, unsigned v) {
  __hip_atomic_store(p, v, __ATOMIC_RELAXED, __HIP_MEMORY_SCOPE_AGENT);
}

// ---------------- prep: tagged zeros for the t=0 state ----------------
// h element format: u32 = (bf16 << 16) | 1.  LSB=1 == "written" (poison 0xAA... is even).
__global__ void prep_zero(unsigned* h0, unsigned* h1, unsigned* hd, float* out) {
  int i = blockIdx.x * blockDim.x + threadIdx.x;
  if (i < 2560) { h0[i] = 1u; h1[i] = 1u; hd[i] = 1u; }   // t=0 slots: 8 x 320 tagged zeros
  if (i == 0) out[0] = 0.f;
}

// ---------------- prep: bf16 conversions + bias folds ----------------
__global__ void prep_w(
    const float* __restrict__ whh0, const float* __restrict__ wih1,
    const float* __restrict__ whh1, const float* __restrict__ whhd,
    const float* __restrict__ wih0, const float* __restrict__ xs,
    const float* __restrict__ ewo,  const float* __restrict__ dwo,
    const float* __restrict__ bih1, const float* __restrict__ bhh1,
    const float* __restrict__ bih0, const float* __restrict__ bhh0,
    ushort* __restrict__ wb, ushort* __restrict__ wih0b, ushort* __restrict__ xsb,
    ushort* __restrict__ wob, ushort* __restrict__ dwob,
    float* __restrict__ bias1p, float* __restrict__ b0s)
{
  int i = blockIdx.x * blockDim.x + threadIdx.x;
  if (i < 1638400) {                       // 4 recurrent-ish mats [1280][320]
    int m = i / 409600, e = i - m * 409600;
    const float* src = (m == 0) ? whh0 : (m == 1) ? wih1 : (m == 2) ? whh1 : whhd;
    wb[i] = f2bf(src[e]);
  } else if (i < 1761280) {                // Wih0 [1280][80] -> [1280][96] zero-padded
    int e = i - 1638400;
    int row = e / 96, k = e - row * 96;
    wih0b[e] = (k < 80) ? f2bf(wih0[row * 80 + k]) : (ushort)0;
  } else if (i < 2145280) {                // xs [4000][80] -> [4000][96] zero-padded
    int e = i - 1761280;
    int row = e / 96, k = e - row * 96;
    xsb[e] = (k < 80) ? f2bf(xs[row * 80 + k]) : (ushort)0;
  } else if (i < 2186240) {                // enc_Wo [128][320]
    int e = i - 2145280;
    wob[e] = f2bf(ewo[e]);
  } else if (i < 2227200) {                // dec_Wo [128][320]
    int e = i - 2186240;
    dwob[e] = f2bf(dwo[e]);
  } else if (i < 2228480) {                // bias1 permuted [unit][gate]
    int e = i - 2227200;
    int uq = e >> 2, gq = e & 3;
    bias1p[e] = bih1[gq * HH + uq] + bhh1[gq * HH + uq];
  } else if (i < 2229760) {                // bih0+bhh0 summed (gate-row order)
    int e = i - 2228480;
    b0s[e] = bih0[e] + bhh0[e];
  }
}

// ---------------- xproj for layer0: [4000,96]bf16 @ [96,1280] -> xp0[b][t][u][g] f32 ----------------
__global__ __launch_bounds__(256) void xproj0_mfma(
    const ushort* __restrict__ xsb, const ushort* __restrict__ wih0b,
    const float* __restrict__ b0s, float* __restrict__ xp0)
{
  const int mt = blockIdx.x;                 // 250 tiles of 16 (b,t)-rows
  const int wave = threadIdx.x >> 6, lane = threadIdx.x & 63;
  const int q = lane >> 4, n16 = lane & 15;
  s8v a[3];
#pragma unroll
  for (int kt = 0; kt < 3; kt++)
    a[kt] = *(const s8v*)(xsb + (mt * 16 + n16) * 96 + kt * 32 + q * 8);
  for (int nt = wave; nt < 80; nt += 4) {
    s8v bf[3];
#pragma unroll
    for (int kt = 0; kt < 3; kt++)
      bf[kt] = *(const s8v*)(wih0b + (nt * 16 + n16) * 96 + kt * 32 + q * 8);
    f4v acc = {0.f, 0.f, 0.f, 0.f};
#pragma unroll
    for (int kt = 0; kt < 3; kt++)
      acc = __builtin_amdgcn_mfma_f32_16x16x32_bf16(a[kt], bf[kt], acc, 0, 0, 0);
    const int gr = nt * 16 + n16;            // D col = gate row
    const int gg = gr / HH;
    const int uu = gr - gg * HH;
    const float bias = b0s[gr];
#pragma unroll
    for (int r = 0; r < 4; r++) {
      int bt = mt * 16 + 4 * q + r;          // D row = (b,t) row
      xp0[(size_t)bt * G4 + uu * 4 + gg] = acc[r] + bias;
    }
  }
}

// ---------------- decoder input projection: one-hot gather ----------------
__global__ __launch_bounds__(256) void xprojd_g(
    const int* __restrict__ ys, const float* __restrict__ dWih,
    const float* __restrict__ dbih, const float* __restrict__ dbhh,
    float* __restrict__ xpd)
{
  const int blk = blockIdx.x;                // 968 = 8 * 121
  const int b = blk / UP1, u = blk - b * UP1;
  int colv = -1;
  if (u > 0) colv = ys[b * UU + (u - 1)] - 1;   // embed row id>=1 -> one-hot at id-1
  for (int i = threadIdx.x; i < G4; i += 256) {
    int uu = i >> 2, gg = i & 3;
    int row = gg * HH + uu;
    float v = dbih[row] + dbhh[row];
    if (colv >= 0) v += dWih[row * 127 + colv];
    xpd[((size_t)b * UP1 + u) * G4 + i] = v;
  }
}

// ---------------- fused recurrences, 3 stages x 10 wgs (256 thr) ----------------
// stage 0: L0   h0[t+1] = cell(Whh0@h0[t] + xp0[t])
// stage 1: L1   h1[t+1] = cell(Whh1@h1[t] + Wih1@h0[t+1] + b1)   (20 MFMAs)
// stage 2: dec  hd[t+1] = cell(Whhd@hd[t] + xpd[t]), 121 steps
// Transport: write-once tagged u32 words; consumers poll the exact words they
// consume until every LSB==1. No flags, no fences, no ordering assumptions.
__global__ __launch_bounds__(256, 1) void lstm_fused(
    const ushort* __restrict__ wb, const float* __restrict__ bias1p,
    const float* __restrict__ xp0, const float* __restrict__ xpd,
    unsigned* __restrict__ h0u, unsigned* __restrict__ h1u, unsigned* __restrict__ hdu)
{
  const int wg = blockIdx.x;
  const int stage = wg / 10;
  const int gw = wg - stage * 10;
  const int tid = threadIdx.x;
  const int wave = tid >> 6, lane = tid & 63;
  const int q = lane >> 4, n16 = lane & 15;
  const int uloc = n16 >> 2, g = n16 & 3;
  const int w = gw * 4 + wave;              // wave-in-stage [0,40)
  const int ubase = w * 8;                  // this wave owns units [ubase, ubase+8)
  const int bcol = n16 & 7;
  const bool act = (n16 < BB);
  const bool two = (stage == 1);

  const ushort* A = wb + (stage == 0 ? 0 : (stage == 1 ? 819200 : 1228800));
  s8v afr[2][10], ainfr[2][10];
#pragma unroll
  for (int tile = 0; tile < 2; tile++) {
    const int arow = g * HH + ubase + tile * 4 + uloc;
#pragma unroll
    for (int kt = 0; kt < 10; kt++)
      afr[tile][kt] = *(const s8v*)(A + arow * HH + kt * 32 + q * 8);
  }
  if (two) {
    const ushort* Win = wb + 409600;        // Wih1
#pragma unroll
    for (int tile = 0; tile < 2; tile++) {
      const int arow = g * HH + ubase + tile * 4 + uloc;
#pragma unroll
      for (int kt = 0; kt < 10; kt++)
        ainfr[tile][kt] = *(const s8v*)(Win + arow * HH + kt * 32 + q * 8);
    }
  }

  const int steps = (stage == 2) ? UP1 : TT;
  unsigned* hin  = (stage == 0) ? h0u : ((stage == 1) ? h1u : hdu);
  unsigned* hout = hin;

  f4v bias4[2];
  const float* xq = 0;
  if (stage == 0)      xq = xp0 + (size_t)bcol * TT * G4;
  else if (stage == 2) xq = xpd + (size_t)bcol * UP1 * G4;
  else {
#pragma unroll
    for (int tile = 0; tile < 2; tile++)
      bias4[tile] = *(const f4v*)(bias1p + (ubase + tile * 4 + q) * 4);
  }

  const unsigned long long TAGM = 0x0000000100000001ull;
  float c0 = 0.f, c1 = 0.f;

  for (int t = 0; t < steps; t++) {
    // ---- poll + load the h words this wave consumes ----
    const unsigned long long* hpS =
        (const unsigned long long*)hin + (size_t)t * 1280 + n16 * 160 + q * 4;
    const unsigned long long* hpI =
        (const unsigned long long*)h0u + (size_t)(t + 1) * 1280 + n16 * 160 + q * 4;
    unsigned long long raw[40], rawB[40];
    int tries = 0;
    for (;;) {
      if (act) {
#pragma unroll
        for (int kt = 0; kt < 10; kt++)
#pragma unroll
          for (int j = 0; j < 4; j++)
            raw[kt * 4 + j] = ald64(hpS + kt * 16 + j);
        if (two) {
#pragma unroll
          for (int kt = 0; kt < 10; kt++)
#pragma unroll
            for (int j = 0; j < 4; j++)
              rawB[kt * 4 + j] = ald64(hpI + kt * 16 + j);
        }
      }
      unsigned long long a = TAGM;
      if (act) {
        a = raw[0];
#pragma unroll
        for (int i = 1; i < 40; i++) a &= raw[i];
        if (two) {
#pragma unroll
          for (int i = 0; i < 40; i++) a &= rawB[i];
        }
      }
      int ok = ((a & TAGM) == TAGM);
      if (__all(ok)) break;
      if (++tries > (1 << 16)) break;       // terminate rather than hang
      __builtin_amdgcn_s_sleep(1);
    }

    // ---- pack bf16 B-fragments (bf16 sits in high 16 of each u32) ----
    union F { unsigned u[4]; s8v v; };
    F bS[10], bI[10];
#pragma unroll
    for (int kt = 0; kt < 10; kt++)
#pragma unroll
      for (int j = 0; j < 4; j++) {
        unsigned long long r = raw[kt * 4 + j];
        unsigned lo = (unsigned)r, hi = (unsigned)(r >> 32);
        bS[kt].u[j] = act ? ((lo >> 16) | (hi & 0xFFFF0000u)) : 0u;
      }
    if (two) {
#pragma unroll
      for (int kt = 0; kt < 10; kt++)
#pragma unroll
        for (int j = 0; j < 4; j++) {
          unsigned long long r = rawB[kt * 4 + j];
          unsigned lo = (unsigned)r, hi = (unsigned)(r >> 32);
          bI[kt].u[j] = act ? ((lo >> 16) | (hi & 0xFFFF0000u)) : 0u;
        }
    }

    // ---- C-init + MFMAs ----
    f4v acc[2];
    if (stage == 1) {
      acc[0] = bias4[0]; acc[1] = bias4[1];
    } else {
#pragma unroll
      for (int tile = 0; tile < 2; tile++)
        acc[tile] = *(const f4v*)(xq + (size_t)t * G4 + (ubase + tile * 4 + q) * 4);
    }
#pragma unroll
    for (int kt = 0; kt < 10; kt++) {
      acc[0] = __builtin_amdgcn_mfma_f32_16x16x32_bf16(afr[0][kt], bS[kt].v, acc[0], 0, 0, 0);
      acc[1] = __builtin_amdgcn_mfma_f32_16x16x32_bf16(afr[1][kt], bS[kt].v, acc[1], 0, 0, 0);
    }
    if (two) {
#pragma unroll
      for (int kt = 0; kt < 10; kt++) {
        acc[0] = __builtin_amdgcn_mfma_f32_16x16x32_bf16(ainfr[0][kt], bI[kt].v, acc[0], 0, 0, 0);
        acc[1] = __builtin_amdgcn_mfma_f32_16x16x32_bf16(ainfr[1][kt], bI[kt].v, acc[1], 0, 0, 0);
      }
    }

    // ---- lane-local LSTM cell: acc[tile] = (i,f,g,o) for unit, batch n16 ----
    float hv0, hv1;
    {
      float ig = sigf(acc[0][0]), fg = sigf(acc[0][1]);
      float gv = tanh_f(acc[0][2]), og = sigf(acc[0][3]);
      c0 = fg * c0 + ig * gv; hv0 = og * tanh_f(c0);
    }
    {
      float ig = sigf(acc[1][0]), fg = sigf(acc[1][1]);
      float gv = tanh_f(acc[1][2]), og = sigf(acc[1][3]);
      c1 = fg * c1 + ig * gv; hv1 = og * tanh_f(c1);
    }
    if (act) {
      unsigned* dst = hout + (size_t)(t + 1) * 2560 + n16 * 320;
      ast32(dst + ubase + q,     (((unsigned)f2bf(hv0)) << 16) | 1u);
      ast32(dst + ubase + 4 + q, (((unsigned)f2bf(hv1)) << 16) | 1u);
    }
  }
}

// ---------------- output projections: h(tagged u32)[16,320] @ Wo^T -> out2[t][16][128] ----------------
__global__ __launch_bounds__(256) void proj_mfma(
    const unsigned* __restrict__ hseq, const ushort* __restrict__ wo,
    const float* __restrict__ bo, float* __restrict__ out2)
{
  const int t = blockIdx.x;
  const int wave = threadIdx.x >> 6, lane = threadIdx.x & 63;
  const int q = lane >> 4, n16 = lane & 15;
  union F { unsigned u[4]; s8v v; };
  F a[10];
  const unsigned long long* hp =
      (const unsigned long long*)hseq + (size_t)(t + 1) * 1280 + n16 * 160 + q * 4;
#pragma unroll
  for (int kt = 0; kt < 10; kt++)
#pragma unroll
    for (int j = 0; j < 4; j++) {
      unsigned long long r = (n16 < BB) ? hp[kt * 16 + j] : 0ull;
      unsigned lo = (unsigned)r, hi = (unsigned)(r >> 32);
      a[kt].u[j] = (lo >> 16) | (hi & 0xFFFF0000u);
    }
  for (int j = 0; j < 2; j++) {
    int nt = wave * 2 + j;
    s8v bf[10];
#pragma unroll
    for (int kt = 0; kt < 10; kt++)
      bf[kt] = *(const s8v*)(wo + (nt * 16 + n16) * HH + kt * 32 + q * 8);
    f4v acc = {0.f, 0.f, 0.f, 0.f};
#pragma unroll
    for (int kt = 0; kt < 10; kt++)
      acc = __builtin_amdgcn_mfma_f32_16x16x32_bf16(a[kt].v, bf[kt], acc, 0, 0, 0);
    int v = nt * 16 + n16;
    float bias = bo[v];
    if (q < 2) {
#pragma unroll
      for (int r = 0; r < 4; r++) {
        int b = 4 * q + r;                   // D row = batch
        out2[((size_t)t * 16 + b) * VV + v] = acc[r] + bias;
      }
    }
  }
}

// ---------------- per-cell logsumexp over V: produce lb[b][t][u], ly[b][t][u] ----------------
__global__ __launch_bounds__(256) void lse_kernel(
    const float* __restrict__ enc2, const float* __restrict__ dec2,
    const int* __restrict__ ys, float* __restrict__ lb, float* __restrict__ ly)
{
  const int blk = blockIdx.x;                // 4000 = 8*500
  const int b = blk / TT, t = blk - b * TT;
  const int wave = threadIdx.x >> 6, lane = threadIdx.x & 63;
  const float* er = enc2 + ((size_t)t * 16 + b) * VV;
  const float e0 = er[lane], e1 = er[lane + 64];
  for (int u = wave; u < UP1; u += 4) {
    const float* dr = dec2 + ((size_t)u * 16 + b) * VV;
    float s0 = e0 + dr[lane], s1 = e1 + dr[lane + 64];
    float mx = fmaxf(s0, s1);
#pragma unroll
    for (int off = 32; off >= 1; off >>= 1) mx = fmaxf(mx, __shfl_xor(mx, off));
    float p = __expf(s0 - mx) + __expf(s1 - mx);
#pragma unroll
    for (int off = 32; off >= 1; off >>= 1) p += __shfl_xor(p, off);
    float lsev = mx + __logf(p);
    if (u < UU) {
      int y = ys[b * UU + u];                // in [1,127]
      float sy = (y < 64) ? __shfl(s0, y) : __shfl(s1, y - 64);
      if (lane == 0) ly[((size_t)b * TT + t) * UU + u] = sy - lsev;
    }
    if (lane == 0) lb[((size_t)b * TT + t) * UP1 + u] = s0 - lsev;  // lane0: v=0
  }
}

// ---------------- anti-diagonal forward DP, one block per sample ----------------
__global__ __launch_bounds__(128) void dp_kernel(
    const float* __restrict__ lb, const float* __restrict__ ly,
    const int* __restrict__ xlen, const int* __restrict__ ylen,
    float* __restrict__ out)
{
  const int b = blockIdx.x;
  const int u = threadIdx.x;
  __shared__ float buf[2][UP1];
  const int tl = xlen[b], ul = ylen[b];
  if (u == 0) buf[0][0] = 0.f;
  __syncthreads();
  const float NEG = -1e30f;
  float nlb = 0.f, nly = 0.f;
  {
    int tn = 1 - u;
    if (u <= UU && tn >= 1 && tn < TT) nlb = lb[((size_t)b * TT + tn - 1) * UP1 + u];
    if (u >= 1 && u <= UU && tn >= 0 && tn < TT) nly = ly[((size_t)b * TT + tn) * UU + (u - 1)];
  }
  for (int d = 1; d <= TT - 1 + UU; d++) {   // up to 619
    float lbv = nlb, lyv = nly;
    {
      int tn = (d + 1) - u;
      nlb = 0.f; nly = 0.f;
      if (u <= UU && tn >= 1 && tn < TT) nlb = lb[((size_t)b * TT + tn - 1) * UP1 + u];
      if (u >= 1 && u <= UU && tn >= 0 && tn < TT) nly = ly[((size_t)b * TT + tn) * UU + (u - 1)];
    }
    const int t = d - u;
    float* cur = buf[d & 1];
    const float* prev = buf[(d & 1) ^ 1];
    if (u <= UU && t >= 0 && t < TT) {
      float a1 = (t >= 1) ? prev[u] + lbv : NEG;
      float a2 = (u >= 1) ? prev[u - 1] + lyv : NEG;
      float m = fmaxf(a1, a2);
      float val = (m <= -1e29f) ? NEG : m + __logf(1.f + __expf(-fabsf(a1 - a2)));
      cur[u] = val;
      if (t == tl - 1 && u == ul) {
        float lbt = lb[((size_t)b * TT + t) * UP1 + u];
        atomicAdd(out, -0.125f * (val + lbt));
      }
    }
    __syncthreads();
  }
}

// ---------------- launch ----------------
extern "C" void kernel_launch(void* const* d_in, const int* in_sizes, int n_in,
                              void* d_out, int out_size, void* d_ws, size_t ws_size,
                              hipStream_t stream) {
  (void)in_sizes; (void)n_in; (void)out_size;
  const float* xs    = (const float*)d_in[0];
  const int*   ys    = (const int*)d_in[1];
  const int*   xlen  = (const int*)d_in[2];
  const int*   ylen  = (const int*)d_in[3];
  const float* eWih0 = (const float*)d_in[4];
  const float* eWhh0 = (const float*)d_in[5];
  const float* ebih0 = (const float*)d_in[6];
  const float* ebhh0 = (const float*)d_in[7];
  const float* eWih1 = (const float*)d_in[8];
  const float* eWhh1 = (const float*)d_in[9];
  const float* ebih1 = (const float*)d_in[10];
  const float* ebhh1 = (const float*)d_in[11];
  const float* eWo   = (const float*)d_in[12];
  const float* ebo   = (const float*)d_in[13];
  const float* dWih  = (const float*)d_in[15];
  const float* dWhh  = (const float*)d_in[16];
  const float* dbih  = (const float*)d_in[17];
  const float* dbhh  = (const float*)d_in[18];
  const float* dWo   = (const float*)d_in[19];
  const float* dbo   = (const float*)d_in[20];

  char* ws = (char*)d_ws;
  const size_t OFF_FLAGS = 0;                     // (unused this round)
  const size_t OFF_XP0   = 1024;
  const size_t OFF_XPD   = OFF_XP0   + 20480000;  // 8*500*1280 f32
  const size_t OFF_H0    = OFF_XPD   + 4956160;   // 501 * 8*320 u32 (tagged)
  const size_t OFF_H1    = OFF_H0    + 5130240;
  const size_t OFF_HD    = OFF_H1    + 5130240;   // 122 * 8*320 u32
  const size_t OFF_WB    = OFF_HD    + 1249280;
  const size_t OFF_WIH0B = OFF_WB    + 3276800;   // 4*1280*320 bf16
  const size_t OFF_XSB   = OFF_WIH0B + 245760;    // 1280*96 bf16
  const size_t OFF_WOB   = OFF_XSB   + 768000;    // 4000*96 bf16
  const size_t OFF_DWOB  = OFF_WOB   + 81920;
  const size_t OFF_B1P   = OFF_DWOB  + 81920;
  const size_t OFF_B0S   = OFF_B1P   + 5120;
  const size_t OFF_ENC2  = OFF_B0S   + 5120;
  const size_t OFF_DEC2  = OFF_ENC2  + 4096000;   // 500*16*128 f32
  const size_t OFF_LB    = OFF_DEC2  + 991232;    // 121*16*128 f32
  const size_t OFF_LY    = OFF_LB    + 1936000;   // 8*500*121 f32
  const size_t TOTAL     = OFF_LY    + 1920000;   // 8*500*120 f32
  if (ws_size < TOTAL) return;
  (void)OFF_FLAGS;

  float*    xp0   = (float*)(ws + OFF_XP0);
  float*    xpd   = (float*)(ws + OFF_XPD);
  unsigned* h0    = (unsigned*)(ws + OFF_H0);
  unsigned* h1    = (unsigned*)(ws + OFF_H1);
  unsigned* hd    = (unsigned*)(ws + OFF_HD);
  ushort*   wb    = (ushort*)(ws + OFF_WB);
  ushort*   wih0b = (ushort*)(ws + OFF_WIH0B);
  ushort*   xsb   = (ushort*)(ws + OFF_XSB);
  ushort*   wob   = (ushort*)(ws + OFF_WOB);
  ushort*   dwob  = (ushort*)(ws + OFF_DWOB);
  float*    b1p   = (float*)(ws + OFF_B1P);
  float*    b0s   = (float*)(ws + OFF_B0S);
  float*    enc2  = (float*)(ws + OFF_ENC2);
  float*    dec2  = (float*)(ws + OFF_DEC2);
  float*    lb    = (float*)(ws + OFF_LB);
  float*    ly    = (float*)(ws + OFF_LY);
  float*    out   = (float*)d_out;

  hipLaunchKernelGGL(prep_zero, dim3(10), dim3(256), 0, stream, h0, h1, hd, out);
  hipLaunchKernelGGL(prep_w, dim3(8710), dim3(256), 0, stream,
                     eWhh0, eWih1, eWhh1, dWhh, eWih0, xs, eWo, dWo,
                     ebih1, ebhh1, ebih0, ebhh0,
                     wb, wih0b, xsb, wob, dwob, b1p, b0s);
  hipLaunchKernelGGL(xproj0_mfma, dim3(250), dim3(256), 0, stream, xsb, wih0b, b0s, xp0);
  hipLaunchKernelGGL(xprojd_g, dim3(968), dim3(256), 0, stream, ys, dWih, dbih, dbhh, xpd);
  hipLaunchKernelGGL(lstm_fused, dim3(30), dim3(256), 0, stream,
                     wb, b1p, xp0, xpd, h0, h1, hd);
  hipLaunchKernelGGL(proj_mfma, dim3(500), dim3(256), 0, stream, h1, wob, ebo, enc2);
  hipLaunchKernelGGL(proj_mfma, dim3(121), dim3(256), 0, stream, hd, dwob, dbo, dec2);
  hipLaunchKernelGGL(lse_kernel, dim3(4000), dim3(256), 0, stream, enc2, dec2, ys, lb, ly);
  hipLaunchKernelGGL(dp_kernel, dim3(8), dim3(128), 0, stream, lb, ly, xlen, ylen, out);
}

// Round 4
// 2920.142 us; speedup vs baseline: 2.1594x; 2.1594x over previous
//
#include <hip/hip_runtime.h>

typedef __attribute__((ext_vector_type(8))) short s8v;   // 8 x bf16 (4 VGPRs)
typedef __attribute__((ext_vector_type(4))) float f4v;   // MFMA accumulator

#define BB 8
#define TT 500
#define UU 120
#define UP1 121
#define VV 128
#define HH 320
#define G4 1280

// ---------------- helpers ----------------
__device__ __forceinline__ unsigned short f2bf(float x) {
  unsigned u = __builtin_bit_cast(unsigned, x);
  unsigned r = (u + 0x7FFFu + ((u >> 16) & 1u)) >> 16;  // RNE
  return (unsigned short)r;
}
__device__ __forceinline__ float sigf(float x)   { return 1.f / (1.f + __expf(-x)); }
__device__ __forceinline__ float tanh_f(float x) { return 2.f / (1.f + __expf(-2.f * x)) - 1.f; }

// relaxed agent-scope atomics: sc1 path, bypass stale L1/L2, no cache maintenance
__device__ __forceinline__ unsigned ald32(const unsigned* p) {
  return __hip_atomic_load((unsigned*)p, __ATOMIC_RELAXED, __HIP_MEMORY_SCOPE_AGENT);
}
__device__ __forceinline__ void ast32(unsigned* p, unsigned v) {
  __hip_atomic_store(p, v, __ATOMIC_RELAXED, __HIP_MEMORY_SCOPE_AGENT);
}

// ---------------- prep: tagged zeros for the t=0 state ----------------
// h element format: u32 = (bf16 << 16) | 1.  LSB=1 == "written" (poison 0xAA... is even).
__global__ void prep_zero(unsigned* h0, unsigned* h1, unsigned* hd, float* out) {
  int i = blockIdx.x * blockDim.x + threadIdx.x;
  if (i < 2560) { h0[i] = 1u; h1[i] = 1u; hd[i] = 1u; }   // t=0 slots: 8 x 320 tagged zeros
  if (i == 0) out[0] = 0.f;
}

// ---------------- prep: bf16 conversions + bias folds ----------------
__global__ void prep_w(
    const float* __restrict__ whh0, const float* __restrict__ wih1,
    const float* __restrict__ whh1, const float* __restrict__ whhd,
    const float* __restrict__ wih0, const float* __restrict__ xs,
    const float* __restrict__ ewo,  const float* __restrict__ dwo,
    const float* __restrict__ bih1, const float* __restrict__ bhh1,
    const float* __restrict__ bih0, const float* __restrict__ bhh0,
    ushort* __restrict__ wb, ushort* __restrict__ wih0b, ushort* __restrict__ xsb,
    ushort* __restrict__ wob, ushort* __restrict__ dwob,
    float* __restrict__ bias1p, float* __restrict__ b0s)
{
  int i = blockIdx.x * blockDim.x + threadIdx.x;
  if (i < 1638400) {                       // 4 recurrent-ish mats [1280][320]
    int m = i / 409600, e = i - m * 409600;
    const float* src = (m == 0) ? whh0 : (m == 1) ? wih1 : (m == 2) ? whh1 : whhd;
    wb[i] = f2bf(src[e]);
  } else if (i < 1761280) {                // Wih0 [1280][80] -> [1280][96] zero-padded
    int e = i - 1638400;
    int row = e / 96, k = e - row * 96;
    wih0b[e] = (k < 80) ? f2bf(wih0[row * 80 + k]) : (ushort)0;
  } else if (i < 2145280) {                // xs [4000][80] -> [4000][96] zero-padded
    int e = i - 1761280;
    int row = e / 96, k = e - row * 96;
    xsb[e] = (k < 80) ? f2bf(xs[row * 80 + k]) : (ushort)0;
  } else if (i < 2186240) {                // enc_Wo [128][320]
    int e = i - 2145280;
    wob[e] = f2bf(ewo[e]);
  } else if (i < 2227200) {                // dec_Wo [128][320]
    int e = i - 2186240;
    dwob[e] = f2bf(dwo[e]);
  } else if (i < 2228480) {                // bias1 permuted [unit][gate]
    int e = i - 2227200;
    int uq = e >> 2, gq = e & 3;
    bias1p[e] = bih1[gq * HH + uq] + bhh1[gq * HH + uq];
  } else if (i < 2229760) {                // bih0+bhh0 summed (gate-row order)
    int e = i - 2228480;
    b0s[e] = bih0[e] + bhh0[e];
  }
}

// ---------------- xproj for layer0: [4000,96]bf16 @ [96,1280] -> xp0[b][t][u][g] f32 ----------------
__global__ __launch_bounds__(256) void xproj0_mfma(
    const ushort* __restrict__ xsb, const ushort* __restrict__ wih0b,
    const float* __restrict__ b0s, float* __restrict__ xp0)
{
  const int mt = blockIdx.x;                 // 250 tiles of 16 (b,t)-rows
  const int wave = threadIdx.x >> 6, lane = threadIdx.x & 63;
  const int q = lane >> 4, n16 = lane & 15;
  s8v a[3];
#pragma unroll
  for (int kt = 0; kt < 3; kt++)
    a[kt] = *(const s8v*)(xsb + (mt * 16 + n16) * 96 + kt * 32 + q * 8);
  for (int nt = wave; nt < 80; nt += 4) {
    s8v bf[3];
#pragma unroll
    for (int kt = 0; kt < 3; kt++)
      bf[kt] = *(const s8v*)(wih0b + (nt * 16 + n16) * 96 + kt * 32 + q * 8);
    f4v acc = {0.f, 0.f, 0.f, 0.f};
#pragma unroll
    for (int kt = 0; kt < 3; kt++)
      acc = __builtin_amdgcn_mfma_f32_16x16x32_bf16(a[kt], bf[kt], acc, 0, 0, 0);
    const int gr = nt * 16 + n16;            // D col = gate row
    const int gg = gr / HH;
    const int uu = gr - gg * HH;
    const float bias = b0s[gr];
#pragma unroll
    for (int r = 0; r < 4; r++) {
      int bt = mt * 16 + 4 * q + r;          // D row = (b,t) row
      xp0[(size_t)bt * G4 + uu * 4 + gg] = acc[r] + bias;
    }
  }
}

// ---------------- decoder input projection: one-hot gather ----------------
__global__ __launch_bounds__(256) void xprojd_g(
    const int* __restrict__ ys, const float* __restrict__ dWih,
    const float* __restrict__ dbih, const float* __restrict__ dbhh,
    float* __restrict__ xpd)
{
  const int blk = blockIdx.x;                // 968 = 8 * 121
  const int b = blk / UP1, u = blk - b * UP1;
  int colv = -1;
  if (u > 0) colv = ys[b * UU + (u - 1)] - 1;   // embed row id>=1 -> one-hot at id-1
  for (int i = threadIdx.x; i < G4; i += 256) {
    int uu = i >> 2, gg = i & 3;
    int row = gg * HH + uu;
    float v = dbih[row] + dbhh[row];
    if (colv >= 0) v += dWih[row * 127 + colv];
    xpd[((size_t)b * UP1 + u) * G4 + i] = v;
  }
}

// ---------------- fused recurrences, 3 stages x 5 wgs (512 thr = 8 waves) ----------------
// stage 0: L0   h0[t+1] = cell(Whh0@h0[t] + xp0[t])
// stage 1: L1   h1[t+1] = cell(Whh1@h1[t] + Wih1@h0[t+1] + b1)   (K=640 fused)
// stage 2: dec  hd[t+1] = cell(Whhd@hd[t] + xpd[t]), 121 steps
// Transport: write-once tagged u32 (proven r3). NEW: per-wave disjoint poll
// slices (wave w polls batch-row w only: 5 coalesced u32/lane) + tag-strip into
// double-buffered LDS tile; compute waves read B-frags from LDS. Kills the
// round-3 L3 poll storm.
__global__ __launch_bounds__(512, 1) void lstm_fused(
    const ushort* __restrict__ wb, const float* __restrict__ bias1p,
    const float* __restrict__ xp0, const float* __restrict__ xpd,
    unsigned* __restrict__ h0u, unsigned* __restrict__ h1u, unsigned* __restrict__ hdu)
{
  const int wg = blockIdx.x;
  const int stage = wg / 5;
  const int gw = wg - stage * 5;
  const int tid = threadIdx.x;
  const int wave = tid >> 6, lane = tid & 63;
  const int q = lane >> 4, n16 = lane & 15;
  const int uloc = n16 >> 2, g = n16 & 3;
  const int w = gw * 8 + wave;              // wave-in-stage [0,40)
  const int ubase = w * 8;                  // this wave owns units [ubase, ubase+8)
  const int bcol = n16 & 7;
  const bool act = (n16 < BB);
  const bool two = (stage == 1);

  __shared__ ushort hbS[2][16][328];        // double-buffered h (recurrent input)
  __shared__ ushort hbI[2][16][328];        // stage 1 only: h0[t+1] input

  // zero rows 8..15 once (these feed the unused MFMA B-columns)
  for (int i = tid; i < 8 * 328; i += 512) {
    int r = 8 + i / 328, ci = i % 328;
    hbS[0][r][ci] = 0; hbS[1][r][ci] = 0;
    hbI[0][r][ci] = 0; hbI[1][r][ci] = 0;
  }

  const ushort* A = wb + (stage == 0 ? 0 : (stage == 1 ? 819200 : 1228800));
  s8v afr[2][10], ainfr[2][10];
#pragma unroll
  for (int tile = 0; tile < 2; tile++) {
    const int arow = g * HH + ubase + tile * 4 + uloc;
#pragma unroll
    for (int kt = 0; kt < 10; kt++)
      afr[tile][kt] = *(const s8v*)(A + arow * HH + kt * 32 + q * 8);
  }
  if (two) {
    const ushort* Win = wb + 409600;        // Wih1
#pragma unroll
    for (int tile = 0; tile < 2; tile++) {
      const int arow = g * HH + ubase + tile * 4 + uloc;
#pragma unroll
      for (int kt = 0; kt < 10; kt++)
        ainfr[tile][kt] = *(const s8v*)(Win + arow * HH + kt * 32 + q * 8);
    }
  }

  const int steps = (stage == 2) ? UP1 : TT;
  unsigned* hio = (stage == 0) ? h0u : ((stage == 1) ? h1u : hdu);

  f4v bias4[2];
  const float* xq = 0;
  if (stage == 0)      xq = xp0 + (size_t)bcol * TT * G4;
  else if (stage == 2) xq = xpd + (size_t)bcol * UP1 * G4;
  else {
#pragma unroll
    for (int tile = 0; tile < 2; tile++)
      bias4[tile] = *(const f4v*)(bias1p + (ubase + tile * 4 + q) * 4);
  }

  float c0 = 0.f, c1 = 0.f;
  __syncthreads();                          // LDS zero-init visible

  for (int t = 0; t < steps; t++) {
    const int pb = t & 1;

    // ---- wave w polls batch-row w of the needed h buffers, relays into LDS ----
    {
      const unsigned* src = hio + (size_t)t * 2560 + wave * 320;
      unsigned v[5];
      int tries = 0;
      for (;;) {
#pragma unroll
        for (int j = 0; j < 5; j++) v[j] = ald32(src + j * 64 + lane);
        unsigned a = v[0] & v[1] & v[2] & v[3] & v[4];
        if (__all((int)(a & 1u)) || ++tries > (1 << 17)) break;
        __builtin_amdgcn_s_sleep(2);
      }
#pragma unroll
      for (int j = 0; j < 5; j++) hbS[pb][wave][j * 64 + lane] = (ushort)(v[j] >> 16);
    }
    if (two) {
      const unsigned* src = h0u + (size_t)(t + 1) * 2560 + wave * 320;
      unsigned v[5];
      int tries = 0;
      for (;;) {
#pragma unroll
        for (int j = 0; j < 5; j++) v[j] = ald32(src + j * 64 + lane);
        unsigned a = v[0] & v[1] & v[2] & v[3] & v[4];
        if (__all((int)(a & 1u)) || ++tries > (1 << 17)) break;
        __builtin_amdgcn_s_sleep(2);
      }
#pragma unroll
      for (int j = 0; j < 5; j++) hbI[pb][wave][j * 64 + lane] = (ushort)(v[j] >> 16);
    }
    __syncthreads();

    // ---- C-init ----
    f4v acc[2];
    if (stage == 1) {
      acc[0] = bias4[0]; acc[1] = bias4[1];
    } else {
#pragma unroll
      for (int tile = 0; tile < 2; tile++)
        acc[tile] = *(const f4v*)(xq + (size_t)t * G4 + (ubase + tile * 4 + q) * 4);
    }

    // ---- B-frags straight from LDS + MFMAs ----
#pragma unroll
    for (int kt = 0; kt < 10; kt++) {
      s8v b = *(const s8v*)&hbS[pb][n16][kt * 32 + q * 8];
      acc[0] = __builtin_amdgcn_mfma_f32_16x16x32_bf16(afr[0][kt], b, acc[0], 0, 0, 0);
      acc[1] = __builtin_amdgcn_mfma_f32_16x16x32_bf16(afr[1][kt], b, acc[1], 0, 0, 0);
    }
    if (two) {
#pragma unroll
      for (int kt = 0; kt < 10; kt++) {
        s8v b = *(const s8v*)&hbI[pb][n16][kt * 32 + q * 8];
        acc[0] = __builtin_amdgcn_mfma_f32_16x16x32_bf16(ainfr[0][kt], b, acc[0], 0, 0, 0);
        acc[1] = __builtin_amdgcn_mfma_f32_16x16x32_bf16(ainfr[1][kt], b, acc[1], 0, 0, 0);
      }
    }

    // ---- lane-local LSTM cell: acc[tile] = (i,f,g,o) for unit ubase+tile*4+q, batch n16 ----
    float hv0, hv1;
    {
      float ig = sigf(acc[0][0]), fg = sigf(acc[0][1]);
      float gv = tanh_f(acc[0][2]), og = sigf(acc[0][3]);
      c0 = fg * c0 + ig * gv; hv0 = og * tanh_f(c0);
    }
    {
      float ig = sigf(acc[1][0]), fg = sigf(acc[1][1]);
      float gv = tanh_f(acc[1][2]), og = sigf(acc[1][3]);
      c1 = fg * c1 + ig * gv; hv1 = og * tanh_f(c1);
    }
    if (act) {
      unsigned* dst = hio + (size_t)(t + 1) * 2560 + n16 * 320;
      ast32(dst + ubase + q,     (((unsigned)f2bf(hv0)) << 16) | 1u);
      ast32(dst + ubase + 4 + q, (((unsigned)f2bf(hv1)) << 16) | 1u);
    }
  }
}

// ---------------- output projections: h(tagged u32)[16,320] @ Wo^T -> out2[t][16][128] ----------------
__global__ __launch_bounds__(256) void proj_mfma(
    const unsigned* __restrict__ hseq, const ushort* __restrict__ wo,
    const float* __restrict__ bo, float* __restrict__ out2)
{
  const int t = blockIdx.x;
  const int wave = threadIdx.x >> 6, lane = threadIdx.x & 63;
  const int q = lane >> 4, n16 = lane & 15;
  union F { unsigned u[4]; s8v v; };
  F a[10];
  const unsigned long long* hp =
      (const unsigned long long*)hseq + (size_t)(t + 1) * 1280 + n16 * 160 + q * 4;
#pragma unroll
  for (int kt = 0; kt < 10; kt++)
#pragma unroll
    for (int j = 0; j < 4; j++) {
      unsigned long long r = (n16 < BB) ? hp[kt * 16 + j] : 0ull;
      unsigned lo = (unsigned)r, hi = (unsigned)(r >> 32);
      a[kt].u[j] = (lo >> 16) | (hi & 0xFFFF0000u);
    }
  for (int j = 0; j < 2; j++) {
    int nt = wave * 2 + j;
    s8v bf[10];
#pragma unroll
    for (int kt = 0; kt < 10; kt++)
      bf[kt] = *(const s8v*)(wo + (nt * 16 + n16) * HH + kt * 32 + q * 8);
    f4v acc = {0.f, 0.f, 0.f, 0.f};
#pragma unroll
    for (int kt = 0; kt < 10; kt++)
      acc = __builtin_amdgcn_mfma_f32_16x16x32_bf16(a[kt].v, bf[kt], acc, 0, 0, 0);
    int v = nt * 16 + n16;
    float bias = bo[v];
    if (q < 2) {
#pragma unroll
      for (int r = 0; r < 4; r++) {
        int b = 4 * q + r;                   // D row = batch
        out2[((size_t)t * 16 + b) * VV + v] = acc[r] + bias;
      }
    }
  }
}

// ---------------- per-cell logsumexp over V: produce lb[b][t][u], ly[b][t][u] ----------------
__global__ __launch_bounds__(256) void lse_kernel(
    const float* __restrict__ enc2, const float* __restrict__ dec2,
    const int* __restrict__ ys, float* __restrict__ lb, float* __restrict__ ly)
{
  const int blk = blockIdx.x;                // 4000 = 8*500
  const int b = blk / TT, t = blk - b * TT;
  const int wave = threadIdx.x >> 6, lane = threadIdx.x & 63;
  const float* er = enc2 + ((size_t)t * 16 + b) * VV;
  const float e0 = er[lane], e1 = er[lane + 64];
  for (int u = wave; u < UP1; u += 4) {
    const float* dr = dec2 + ((size_t)u * 16 + b) * VV;
    float s0 = e0 + dr[lane], s1 = e1 + dr[lane + 64];
    float mx = fmaxf(s0, s1);
#pragma unroll
    for (int off = 32; off >= 1; off >>= 1) mx = fmaxf(mx, __shfl_xor(mx, off));
    float p = __expf(s0 - mx) + __expf(s1 - mx);
#pragma unroll
    for (int off = 32; off >= 1; off >>= 1) p += __shfl_xor(p, off);
    float lsev = mx + __logf(p);
    if (u < UU) {
      int y = ys[b * UU + u];                // in [1,127]
      float sy = (y < 64) ? __shfl(s0, y) : __shfl(s1, y - 64);
      if (lane == 0) ly[((size_t)b * TT + t) * UU + u] = sy - lsev;
    }
    if (lane == 0) lb[((size_t)b * TT + t) * UP1 + u] = s0 - lsev;  // lane0: v=0
  }
}

// ---------------- anti-diagonal forward DP, one block per sample ----------------
__global__ __launch_bounds__(128) void dp_kernel(
    const float* __restrict__ lb, const float* __restrict__ ly,
    const int* __restrict__ xlen, const int* __restrict__ ylen,
    float* __restrict__ out)
{
  const int b = blockIdx.x;
  const int u = threadIdx.x;
  __shared__ float buf[2][UP1];
  const int tl = xlen[b], ul = ylen[b];
  if (u == 0) buf[0][0] = 0.f;
  __syncthreads();
  const float NEG = -1e30f;
  float nlb = 0.f, nly = 0.f;
  {
    int tn = 1 - u;
    if (u <= UU && tn >= 1 && tn < TT) nlb = lb[((size_t)b * TT + tn - 1) * UP1 + u];
    if (u >= 1 && u <= UU && tn >= 0 && tn < TT) nly = ly[((size_t)b * TT + tn) * UU + (u - 1)];
  }
  for (int d = 1; d <= TT - 1 + UU; d++) {   // up to 619
    float lbv = nlb, lyv = nly;
    {
      int tn = (d + 1) - u;
      nlb = 0.f; nly = 0.f;
      if (u <= UU && tn >= 1 && tn < TT) nlb = lb[((size_t)b * TT + tn - 1) * UP1 + u];
      if (u >= 1 && u <= UU && tn >= 0 && tn < TT) nly = ly[((size_t)b * TT + tn) * UU + (u - 1)];
    }
    const int t = d - u;
    float* cur = buf[d & 1];
    const float* prev = buf[(d & 1) ^ 1];
    if (u <= UU && t >= 0 && t < TT) {
      float a1 = (t >= 1) ? prev[u] + lbv : NEG;
      float a2 = (u >= 1) ? prev[u - 1] + lyv : NEG;
      float m = fmaxf(a1, a2);
      float val = (m <= -1e29f) ? NEG : m + __logf(1.f + __expf(-fabsf(a1 - a2)));
      cur[u] = val;
      if (t == tl - 1 && u == ul) {
        float lbt = lb[((size_t)b * TT + t) * UP1 + u];
        atomicAdd(out, -0.125f * (val + lbt));
      }
    }
    __syncthreads();
  }
}

// ---------------- launch ----------------
extern "C" void kernel_launch(void* const* d_in, const int* in_sizes, int n_in,
                              void* d_out, int out_size, void* d_ws, size_t ws_size,
                              hipStream_t stream) {
  (void)in_sizes; (void)n_in; (void)out_size;
  const float* xs    = (const float*)d_in[0];
  const int*   ys    = (const int*)d_in[1];
  const int*   xlen  = (const int*)d_in[2];
  const int*   ylen  = (const int*)d_in[3];
  const float* eWih0 = (const float*)d_in[4];
  const float* eWhh0 = (const float*)d_in[5];
  const float* ebih0 = (const float*)d_in[6];
  const float* ebhh0 = (const float*)d_in[7];
  const float* eWih1 = (const float*)d_in[8];
  const float* eWhh1 = (const float*)d_in[9];
  const float* ebih1 = (const float*)d_in[10];
  const float* ebhh1 = (const float*)d_in[11];
  const float* eWo   = (const float*)d_in[12];
  const float* ebo   = (const float*)d_in[13];
  const float* dWih  = (const float*)d_in[15];
  const float* dWhh  = (const float*)d_in[16];
  const float* dbih  = (const float*)d_in[17];
  const float* dbhh  = (const float*)d_in[18];
  const float* dWo   = (const float*)d_in[19];
  const float* dbo   = (const float*)d_in[20];

  char* ws = (char*)d_ws;
  const size_t OFF_XP0   = 1024;
  const size_t OFF_XPD   = OFF_XP0   + 20480000;  // 8*500*1280 f32
  const size_t OFF_H0    = OFF_XPD   + 4956160;   // 501 * 8*320 u32 (tagged)
  const size_t OFF_H1    = OFF_H0    + 5130240;
  const size_t OFF_HD    = OFF_H1    + 5130240;   // 122 * 8*320 u32
  const size_t OFF_WB    = OFF_HD    + 1249280;
  const size_t OFF_WIH0B = OFF_WB    + 3276800;   // 4*1280*320 bf16
  const size_t OFF_XSB   = OFF_WIH0B + 245760;    // 1280*96 bf16
  const size_t OFF_WOB   = OFF_XSB   + 768000;    // 4000*96 bf16
  const size_t OFF_DWOB  = OFF_WOB   + 81920;
  const size_t OFF_B1P   = OFF_DWOB  + 81920;
  const size_t OFF_B0S   = OFF_B1P   + 5120;
  const size_t OFF_ENC2  = OFF_B0S   + 5120;
  const size_t OFF_DEC2  = OFF_ENC2  + 4096000;   // 500*16*128 f32
  const size_t OFF_LB    = OFF_DEC2  + 991232;    // 121*16*128 f32
  const size_t OFF_LY    = OFF_LB    + 1936000;   // 8*500*121 f32
  const size_t TOTAL     = OFF_LY    + 1920000;   // 8*500*120 f32
  if (ws_size < TOTAL) return;

  float*    xp0   = (float*)(ws + OFF_XP0);
  float*    xpd   = (float*)(ws + OFF_XPD);
  unsigned* h0    = (unsigned*)(ws + OFF_H0);
  unsigned* h1    = (unsigned*)(ws + OFF_H1);
  unsigned* hd    = (unsigned*)(ws + OFF_HD);
  ushort*   wb    = (ushort*)(ws + OFF_WB);
  ushort*   wih0b = (ushort*)(ws + OFF_WIH0B);
  ushort*   xsb   = (ushort*)(ws + OFF_XSB);
  ushort*   wob   = (ushort*)(ws + OFF_WOB);
  ushort*   dwob  = (ushort*)(ws + OFF_DWOB);
  float*    b1p   = (float*)(ws + OFF_B1P);
  float*    b0s   = (float*)(ws + OFF_B0S);
  float*    enc2  = (float*)(ws + OFF_ENC2);
  float*    dec2  = (float*)(ws + OFF_DEC2);
  float*    lb    = (float*)(ws + OFF_LB);
  float*    ly    = (float*)(ws + OFF_LY);
  float*    out   = (float*)d_out;

  hipLaunchKernelGGL(prep_zero, dim3(10), dim3(256), 0, stream, h0, h1, hd, out);
  hipLaunchKernelGGL(prep_w, dim3(8710), dim3(256), 0, stream,
                     eWhh0, eWih1, eWhh1, dWhh, eWih0, xs, eWo, dWo,
                     ebih1, ebhh1, ebih0, ebhh0,
                     wb, wih0b, xsb, wob, dwob, b1p, b0s);
  hipLaunchKernelGGL(xproj0_mfma, dim3(250), dim3(256), 0, stream, xsb, wih0b, b0s, xp0);
  hipLaunchKernelGGL(xprojd_g, dim3(968), dim3(256), 0, stream, ys, dWih, dbih, dbhh, xpd);
  hipLaunchKernelGGL(lstm_fused, dim3(15), dim3(512), 0, stream,
                     wb, b1p, xp0, xpd, h0, h1, hd);
  hipLaunchKernelGGL(proj_mfma, dim3(500), dim3(256), 0, stream, h1, wob, ebo, enc2);
  hipLaunchKernelGGL(proj_mfma, dim3(121), dim3(256), 0, stream, hd, dwob, dbo, dec2);
  hipLaunchKernelGGL(lse_kernel, dim3(4000), dim3(256), 0, stream, enc2, dec2, ys, lb, ly);
  hipLaunchKernelGGL(dp_kernel, dim3(8), dim3(128), 0, stream, lb, ly, xlen, ylen, out);
}